// Round 1
// baseline (224.422 us; speedup 1.0000x reference)
//
#include <hip/hip_runtime.h>
#include <hip/hip_bf16.h>

#define BLOCK 256
#define GRID 2048

__global__ __launch_bounds__(BLOCK) void wcl_main_kernel(
    const float4* __restrict__ out4,   // [B] rows of 4 logits
    const int*    __restrict__ tgt,    // [B] targets (0..3)
    const float*  __restrict__ w,      // [16] severity weights, row = true, col = pred
    double*       __restrict__ acc,    // [1] global double accumulator (pre-zeroed)
    int B)
{
    __shared__ float sw[16];
    __shared__ float wave_sums[BLOCK / 64];

    if (threadIdx.x < 16) sw[threadIdx.x] = w[threadIdx.x];
    __syncthreads();

    float local = 0.0f;
    const int stride = gridDim.x * blockDim.x;
    for (int i = blockIdx.x * blockDim.x + threadIdx.x; i < B; i += stride) {
        const float4 x = out4[i];
        const int t = tgt[i];

        // argmax with first-occurrence tie-break (strictly-greater scan)
        float best = x.x; int pred = 0;
        if (x.y > best) { best = x.y; pred = 1; }
        if (x.z > best) { best = x.z; pred = 2; }
        if (x.w > best) { best = x.w; pred = 3; }

        const float sev = sw[t * 4 + pred];

        // cross-entropy = logsumexp(x) - x[t]
        const float s = expf(x.x - best) + expf(x.y - best) +
                        expf(x.z - best) + expf(x.w - best);
        const float lse = best + logf(s);
        const float xt = (t == 0) ? x.x : (t == 1) ? x.y : (t == 2) ? x.z : x.w;

        local += sev + (lse - xt);
    }

    // wave-64 shuffle reduction
    #pragma unroll
    for (int off = 32; off > 0; off >>= 1)
        local += __shfl_down(local, off);

    const int lane = threadIdx.x & 63;
    const int wave = threadIdx.x >> 6;
    if (lane == 0) wave_sums[wave] = local;
    __syncthreads();

    if (threadIdx.x == 0) {
        float bsum = 0.0f;
        #pragma unroll
        for (int i = 0; i < BLOCK / 64; ++i) bsum += wave_sums[i];
        atomicAdd(acc, (double)bsum);
    }
}

__global__ void wcl_final_kernel(const double* __restrict__ acc,
                                 float* __restrict__ out, int B)
{
    out[0] = (float)(acc[0] / (double)B);
}

extern "C" void kernel_launch(void* const* d_in, const int* in_sizes, int n_in,
                              void* d_out, int out_size, void* d_ws, size_t ws_size,
                              hipStream_t stream) {
    const float* outputs = (const float*)d_in[0];   // [B,4] fp32
    const int*   targets = (const int*)d_in[1];     // [B] int
    const float* weights = (const float*)d_in[2];   // [4,4] fp32
    const int B = in_sizes[0] / 4;

    double* acc = (double*)d_ws;
    hipMemsetAsync(d_ws, 0, sizeof(double), stream);

    wcl_main_kernel<<<GRID, BLOCK, 0, stream>>>(
        (const float4*)outputs, targets, weights, acc, B);
    wcl_final_kernel<<<1, 1, 0, stream>>>(acc, (float*)d_out, B);
}

// Round 2
// 207.581 us; speedup vs baseline: 1.0811x; 1.0811x over previous
//
#include <hip/hip_runtime.h>
#include <hip/hip_bf16.h>

#define BLOCK 256
#define GRID 2048

typedef float floatx4 __attribute__((ext_vector_type(4)));

__device__ __forceinline__ float row_loss(floatx4 x, int t, const float* sw) {
    // argmax, first-occurrence tie-break (strictly-greater scan)
    float best = x.x; int pred = 0;
    if (x.y > best) { best = x.y; pred = 1; }
    if (x.z > best) { best = x.z; pred = 2; }
    if (x.w > best) { best = x.w; pred = 3; }
    const float sev = sw[t * 4 + pred];
    const float s = expf(x.x - best) + expf(x.y - best) +
                    expf(x.z - best) + expf(x.w - best);
    const float lse = best + logf(s);
    const float xt = (t == 0) ? x.x : (t == 1) ? x.y : (t == 2) ? x.z : x.w;
    return sev + (lse - xt);
}

__global__ __launch_bounds__(BLOCK) void wcl_main_kernel(
    const floatx4* __restrict__ out4,   // [B] rows of 4 logits
    const int*     __restrict__ tgt,    // [B] targets (0..3)
    const float*   __restrict__ w,      // [16] severity weights
    float*         __restrict__ partials, // [GRID] per-block sums (no pre-zero needed)
    int B)
{
    __shared__ float sw[16];
    __shared__ float wave_sums[BLOCK / 64];

    if (threadIdx.x < 16) sw[threadIdx.x] = w[threadIdx.x];
    __syncthreads();

    const int stride = GRID * BLOCK;
    int i = blockIdx.x * BLOCK + threadIdx.x;

    float local = 0.0f;
    // 4x unrolled: 4 independent float4 + 4 int loads in flight
    while (i + 3 * stride < B) {
        floatx4 x0 = __builtin_nontemporal_load(&out4[i]);
        floatx4 x1 = __builtin_nontemporal_load(&out4[i + stride]);
        floatx4 x2 = __builtin_nontemporal_load(&out4[i + 2 * stride]);
        floatx4 x3 = __builtin_nontemporal_load(&out4[i + 3 * stride]);
        int t0 = __builtin_nontemporal_load(&tgt[i]);
        int t1 = __builtin_nontemporal_load(&tgt[i + stride]);
        int t2 = __builtin_nontemporal_load(&tgt[i + 2 * stride]);
        int t3 = __builtin_nontemporal_load(&tgt[i + 3 * stride]);
        local += row_loss(x0, t0, sw);
        local += row_loss(x1, t1, sw);
        local += row_loss(x2, t2, sw);
        local += row_loss(x3, t3, sw);
        i += 4 * stride;
    }
    while (i < B) {
        floatx4 x = __builtin_nontemporal_load(&out4[i]);
        int t = __builtin_nontemporal_load(&tgt[i]);
        local += row_loss(x, t, sw);
        i += stride;
    }

    // wave-64 shuffle reduction
    #pragma unroll
    for (int off = 32; off > 0; off >>= 1)
        local += __shfl_down(local, off);

    const int lane = threadIdx.x & 63;
    const int wave = threadIdx.x >> 6;
    if (lane == 0) wave_sums[wave] = local;
    __syncthreads();

    if (threadIdx.x == 0) {
        float bsum = 0.0f;
        #pragma unroll
        for (int j = 0; j < BLOCK / 64; ++j) bsum += wave_sums[j];
        partials[blockIdx.x] = bsum;
    }
}

__global__ __launch_bounds__(BLOCK) void wcl_final_kernel(
    const float* __restrict__ partials, float* __restrict__ out, int B)
{
    __shared__ double wave_sums[BLOCK / 64];
    double local = 0.0;
    for (int i = threadIdx.x; i < GRID; i += BLOCK)
        local += (double)partials[i];

    #pragma unroll
    for (int off = 32; off > 0; off >>= 1)
        local += __shfl_down(local, off);

    const int lane = threadIdx.x & 63;
    const int wave = threadIdx.x >> 6;
    if (lane == 0) wave_sums[wave] = local;
    __syncthreads();

    if (threadIdx.x == 0) {
        double s = 0.0;
        #pragma unroll
        for (int j = 0; j < BLOCK / 64; ++j) s += wave_sums[j];
        out[0] = (float)(s / (double)B);
    }
}

extern "C" void kernel_launch(void* const* d_in, const int* in_sizes, int n_in,
                              void* d_out, int out_size, void* d_ws, size_t ws_size,
                              hipStream_t stream) {
    const float* outputs = (const float*)d_in[0];   // [B,4] fp32
    const int*   targets = (const int*)d_in[1];     // [B] int
    const float* weights = (const float*)d_in[2];   // [4,4] fp32
    const int B = in_sizes[0] / 4;

    float* partials = (float*)d_ws;                 // GRID floats

    wcl_main_kernel<<<GRID, BLOCK, 0, stream>>>(
        (const floatx4*)outputs, targets, weights, partials, B);
    wcl_final_kernel<<<1, BLOCK, 0, stream>>>(partials, (float*)d_out, B);
}